// Round 2
// baseline (452.375 us; speedup 1.0000x reference)
//
#include <hip/hip_runtime.h>

// MAGNN metapath instance encoder ('average' rnn_type) for MI355X.
//
// Per edge e:
//   hidden[d512] = mean over first 3 metapath positions of features[idx[e][p]][d512]
//   view as (8 heads, 64 dims); L2-normalize across the HEAD axis:
//     out[h*64+d] = hidden[h*64+d] / max( sqrt( sum_h hidden[h*64+d]^2 ), 1e-12 )
//
// One 64-lane wave per edge. Lane l loads float4s at element offsets
// 4l (head l>>4) and 256+4l (head (l>>4)+4) -> the 8-head column reduction is
// a 4-lane butterfly over {l, l^16, l^32, l^48}.
//
// Output is write-once (268 MB) while the features table (204.8 MB) fits the
// 256 MB Infinity Cache -> nontemporal stores keep the write stream from
// evicting features, so gather re-reads stay LLC-resident.

#define N_EDGES   131072
#define D_DIM     512
#define MP_LEN    4

typedef float v4f __attribute__((ext_vector_type(4)));

__global__ __launch_bounds__(256) void magnn_avg_norm_kernel(
    const float* __restrict__ features,        // (100000, 512) f32
    const int*   __restrict__ idx,             // (131072, 4)  i32
    float*       __restrict__ out)             // (131072, 512) f32
{
    const int lane = threadIdx.x & 63;
    const int wid  = threadIdx.x >> 6;
    const long e   = (long)blockIdx.x * 4 + wid;   // 4 edges per 256-thread block

    // metapath indices (uniform per wave; broadcast via cache)
    const int i0 = idx[e * MP_LEN + 0];
    const int i1 = idx[e * MP_LEN + 1];
    const int i2 = idx[e * MP_LEN + 2];
    // idx[e*MP_LEN+3] (last position) is dropped by edata[:, :-1, :]

    const float4* __restrict__ f4 = (const float4*)features;  // row stride = 128 float4
    const long r0 = (long)i0 * (D_DIM / 4);
    const long r1 = (long)i1 * (D_DIM / 4);
    const long r2 = (long)i2 * (D_DIM / 4);

    // two float4 chunks per lane: elements [4l..4l+3] and [256+4l..256+4l+3]
    float4 a0 = f4[r0 + lane];
    float4 b0 = f4[r1 + lane];
    float4 c0 = f4[r2 + lane];
    float4 a1 = f4[r0 + 64 + lane];
    float4 b1 = f4[r1 + 64 + lane];
    float4 c1 = f4[r2 + 64 + lane];

    const float k = 1.0f / 3.0f;
    float4 h0, h1;
    h0.x = (a0.x + b0.x + c0.x) * k;
    h0.y = (a0.y + b0.y + c0.y) * k;
    h0.z = (a0.z + b0.z + c0.z) * k;
    h0.w = (a0.w + b0.w + c0.w) * k;
    h1.x = (a1.x + b1.x + c1.x) * k;
    h1.y = (a1.y + b1.y + c1.y) * k;
    h1.z = (a1.z + b1.z + c1.z) * k;
    h1.w = (a1.w + b1.w + c1.w) * k;

    // per-column sum of squares over this lane's 2 heads, then butterfly over
    // the 4 lanes {l, l^16, l^32, l^48} that hold the other 6 heads of the
    // same columns -> full 8-head sum.
    float sx = h0.x * h0.x + h1.x * h1.x;
    float sy = h0.y * h0.y + h1.y * h1.y;
    float sz = h0.z * h0.z + h1.z * h1.z;
    float sw = h0.w * h0.w + h1.w * h1.w;

    sx += __shfl_xor(sx, 16);
    sy += __shfl_xor(sy, 16);
    sz += __shfl_xor(sz, 16);
    sw += __shfl_xor(sw, 16);
    sx += __shfl_xor(sx, 32);
    sy += __shfl_xor(sy, 32);
    sz += __shfl_xor(sz, 32);
    sw += __shfl_xor(sw, 32);

    const float rx = 1.0f / fmaxf(sqrtf(sx), 1e-12f);
    const float ry = 1.0f / fmaxf(sqrtf(sy), 1e-12f);
    const float rz = 1.0f / fmaxf(sqrtf(sz), 1e-12f);
    const float rw = 1.0f / fmaxf(sqrtf(sw), 1e-12f);

    v4f o0, o1;
    o0.x = h0.x * rx;  o0.y = h0.y * ry;  o0.z = h0.z * rz;  o0.w = h0.w * rw;
    o1.x = h1.x * rx;  o1.y = h1.y * ry;  o1.z = h1.z * rz;  o1.w = h1.w * rw;

    // nontemporal: output is never re-read; don't evict LLC-resident features
    v4f* __restrict__ o4 = (v4f*)out;
    __builtin_nontemporal_store(o0, o4 + e * (D_DIM / 4) + lane);
    __builtin_nontemporal_store(o1, o4 + e * (D_DIM / 4) + 64 + lane);
}

extern "C" void kernel_launch(void* const* d_in, const int* in_sizes, int n_in,
                              void* d_out, int out_size, void* d_ws, size_t ws_size,
                              hipStream_t stream) {
    const float* features = (const float*)d_in[0];
    const int*   idx      = (const int*)d_in[1];
    float*       out      = (float*)d_out;

    // 4 edges per 256-thread block; 131072 % 4 == 0
    const int grid = N_EDGES / 4;
    magnn_avg_norm_kernel<<<grid, 256, 0, stream>>>(features, idx, out);
}